// Round 1
// baseline (339.391 us; speedup 1.0000x reference)
//
#include <hip/hip_runtime.h>
#include <math.h>

// Problem constants
#define B_    1024
#define D_    768
#define C_    150
#define P_    64
#define TWOD  1536
#define NCLS  151   // C+1
#define NCOL  215   // 151 seen/unseen + 64 u-projection cols

// Workspace layout (float offsets)
#define OFF_MH     0
#define OFF_XH     (C_ * TWOD)                      // 230400
#define OFF_LOGITS (OFF_XH + B_ * TWOD)             // 1803264
#define OFF_U      (OFF_LOGITS + B_ * NCLS)
#define OFF_SQN    (OFF_U + B_ * P_)
#define OFF_PART   (OFF_SQN + B_)
// partials: [0]=cls_sum [1]=pos_sum [2]=pos_cnt [3]=neg_sum [4]=neg_cnt

// ---------------------------------------------------------------------------
// K1/K2: Out[m,n] = sum_k A[m,k] * Bw[n, boff+k]  (+ bias[n])
// A row-major (lda), Bw row-major (ldb). 64x64 tile, BK=16, 256 thr, 4x4/thr.
// ---------------------------------------------------------------------------
__global__ __launch_bounds__(256) void gemm_nt(
    const float* __restrict__ A, int lda, int M,
    const float* __restrict__ Bw, int ldb, int boff,
    const float* __restrict__ bias,
    float* __restrict__ Out, int ldo, int N, int K)
{
    __shared__ float As[16][68];   // [k][m], +4 pad
    __shared__ float Bs[16][68];   // [k][n]
    const int t  = threadIdx.x;
    const int bm = blockIdx.x * 64;
    const int bn = blockIdx.y * 64;
    const int tm = t & 15, tn = t >> 4;
    const int lrow = t >> 2;         // 0..63
    const int lk   = (t & 3) * 4;    // 0,4,8,12

    float acc[4][4] = {};

    for (int k0 = 0; k0 < K; k0 += 16) {
        int gr  = bm + lrow;
        int grc = gr < M ? gr : (M - 1);
        const float4 av = *(const float4*)&A[(size_t)grc * lda + k0 + lk];
        As[lk + 0][lrow] = av.x; As[lk + 1][lrow] = av.y;
        As[lk + 2][lrow] = av.z; As[lk + 3][lrow] = av.w;
        const float4 bv = *(const float4*)&Bw[(size_t)(bn + lrow) * ldb + boff + k0 + lk];
        Bs[lk + 0][lrow] = bv.x; Bs[lk + 1][lrow] = bv.y;
        Bs[lk + 2][lrow] = bv.z; Bs[lk + 3][lrow] = bv.w;
        __syncthreads();
#pragma unroll
        for (int kk = 0; kk < 16; ++kk) {
            const float4 a4 = *(const float4*)&As[kk][tm * 4];
            const float4 b4 = *(const float4*)&Bs[kk][tn * 4];
            const float a[4]  = {a4.x, a4.y, a4.z, a4.w};
            const float bb[4] = {b4.x, b4.y, b4.z, b4.w};
#pragma unroll
            for (int i = 0; i < 4; ++i)
#pragma unroll
                for (int j = 0; j < 4; ++j)
                    acc[i][j] = fmaf(a[i], bb[j], acc[i][j]);
        }
        __syncthreads();
    }

#pragma unroll
    for (int i = 0; i < 4; ++i) {
        int gm = bm + tm * 4 + i;
        if (gm >= M) continue;
#pragma unroll
        for (int j = 0; j < 4; ++j) {
            int gn = bn + tn * 4 + j;
            float bv = bias ? bias[gn] : 0.f;
            Out[(size_t)gm * ldo + gn] = acc[i][j] + bv;
        }
    }
}

// ---------------------------------------------------------------------------
// K3: fused column kernel. Block = 4 b-rows x 64 cols (grid.y chunks).
// col <150: seen_c = sum relu(xh+mh[c])*p1 ; col==150: unseen = sum relu(xh)*p1
// col>=151: u_raw[p] = sum relu(xh)*p2w[p]
// ---------------------------------------------------------------------------
__global__ __launch_bounds__(256) void fused_cols(
    const float* __restrict__ xh,   // [B][1536]
    const float* __restrict__ mh,   // [150][1536]
    const float* __restrict__ p1w,  // [1536]
    const float* __restrict__ p1b,  // [1]
    const float* __restrict__ p2w,  // [64][1536]
    const float* __restrict__ p2b,  // [64]
    float* __restrict__ logits,     // [B][151]
    float* __restrict__ u)          // [B][64]
{
    __shared__ float xs[4 * 1540];  // 4 rows, +4 pad each
    __shared__ float ps[1536];
    const int t  = threadIdx.x;
    const int b0 = blockIdx.x * 4;

    for (int idx = t; idx < 4 * 384; idx += 256) {
        int row = idx / 384, e4 = idx % 384;
        ((float4*)xs)[row * 385 + e4] =
            ((const float4*)xh)[(size_t)(b0 + row) * 384 + e4];
    }
    for (int idx = t; idx < 384; idx += 256)
        ((float4*)ps)[idx] = ((const float4*)p1w)[idx];
    __syncthreads();

    const int bl  = t & 3;
    const int col = blockIdx.y * 64 + (t >> 2);
    const bool active  = col < NCOL;
    const bool is_seen = col < C_;
    const bool is_u    = (col >= NCLS) && active;
    const float4* xr = (const float4*)(xs + bl * 1540);
    const float4* pr = (const float4*)ps;
    const float4* mr = (const float4*)(mh + (size_t)(is_seen ? col : 0) * TWOD);
    const int p = is_u ? (col - NCLS) : 0;
    const float4* wr = (const float4*)(p2w + (size_t)p * TWOD);

    float s0 = 0.f, s1 = 0.f, s2 = 0.f, s3 = 0.f;
    for (int e4 = 0; e4 < 384; ++e4) {
        float4 xv = xr[e4];
        float4 wv = is_u ? wr[e4] : pr[e4];
        if (is_seen) {
            float4 mv = mr[e4];
            xv.x += mv.x; xv.y += mv.y; xv.z += mv.z; xv.w += mv.w;
        }
        s0 = fmaf(fmaxf(xv.x, 0.f), wv.x, s0);
        s1 = fmaf(fmaxf(xv.y, 0.f), wv.y, s1);
        s2 = fmaf(fmaxf(xv.z, 0.f), wv.z, s2);
        s3 = fmaf(fmaxf(xv.w, 0.f), wv.w, s3);
    }
    float acc = (s0 + s1) + (s2 + s3);
    if (active) {
        int gb = b0 + bl;
        if (col < NCLS) logits[(size_t)gb * NCLS + col] = acc + p1b[0];
        else            u[(size_t)gb * P_ + (col - NCLS)] = acc + p2b[col - NCLS];
    }
}

// ---------------------------------------------------------------------------
// K4: row-normalize u, store sq_n. One wave per row.
// ---------------------------------------------------------------------------
__global__ __launch_bounds__(256) void norm_rows(float* __restrict__ u,
                                                 float* __restrict__ sqn)
{
    const int wave = threadIdx.x >> 6;
    const int lane = threadIdx.x & 63;
    const int row  = blockIdx.x * 4 + wave;
    float v = u[(size_t)row * P_ + lane];
    float s = v * v;
#pragma unroll
    for (int off = 32; off; off >>= 1) s += __shfl_xor(s, off);
    float inv = 1.f / fmaxf(sqrtf(s), 1e-12f);
    u[(size_t)row * P_ + lane] = v * inv;
    if (lane == 0) sqn[row] = s * inv * inv;
}

// ---------------------------------------------------------------------------
// K5: classification loss. One wave per row b.
// ---------------------------------------------------------------------------
__global__ __launch_bounds__(256) void cls_loss(const float* __restrict__ logits,
                                                const int* __restrict__ lb,
                                                float* __restrict__ part)
{
    const int wave = threadIdx.x >> 6;
    const int lane = threadIdx.x & 63;
    const int b    = blockIdx.x * 4 + wave;
    const float* row = logits + (size_t)b * NCLS;
    const int l = lb[b];

    float mx = -1e30f;
    for (int j = lane; j < NCLS; j += 64) {
        bool excl = (j == l) && (l < C_);
        float v = row[j];
        if (!excl) mx = fmaxf(mx, v);
    }
#pragma unroll
    for (int off = 32; off; off >>= 1) mx = fmaxf(mx, __shfl_xor(mx, off));
    float se = 0.f;
    for (int j = lane; j < NCLS; j += 64) {
        bool excl = (j == l) && (l < C_);
        if (!excl) se += expf(row[j] - mx);
    }
#pragma unroll
    for (int off = 32; off; off >>= 1) se += __shfl_xor(se, off);

    if (lane == 0) {
        float l150 = row[C_];
        float loss2 = mx + logf(se) - l150;
        float loss1 = 0.f;
        if (l < C_) {
            float a  = row[l];
            float m2 = fmaxf(a, l150);
            loss1 = m2 - a + logf(expf(a - m2) + expf(l150 - m2));
        }
        atomicAdd(part + 0, loss1 + loss2);
    }
}

// ---------------------------------------------------------------------------
// K6: pairwise margin losses. 32x32 pair tile per block, 2x2 per thread.
// ---------------------------------------------------------------------------
__global__ __launch_bounds__(256) void pair_loss(
    const float* __restrict__ u, const float* __restrict__ sqn,
    const int* __restrict__ lb, float* __restrict__ part)
{
    __shared__ float ui[32][68];
    __shared__ float uj[32][68];
    __shared__ float sni[32], snj[32];
    __shared__ int   li[32],  lj[32];
    __shared__ float red[4][4];

    const int t  = threadIdx.x;
    const int i0 = blockIdx.x * 32, j0 = blockIdx.y * 32;

    for (int idx = t; idx < 512; idx += 256) {
        int r = idx >> 4, e4 = idx & 15;
        ((float4*)&ui[r][0])[e4] = ((const float4*)(u + (size_t)(i0 + r) * P_))[e4];
        ((float4*)&uj[r][0])[e4] = ((const float4*)(u + (size_t)(j0 + r) * P_))[e4];
    }
    if (t < 32) {
        sni[t] = sqn[i0 + t]; li[t] = lb[i0 + t];
        snj[t] = sqn[j0 + t]; lj[t] = lb[j0 + t];
    }
    __syncthreads();

    const int ti = (t & 15) * 2, tj = (t >> 4) * 2;
    float dot[2][2] = {};
#pragma unroll
    for (int k = 0; k < 64; k += 4) {
        float4 a0 = *(const float4*)&ui[ti][k];
        float4 a1 = *(const float4*)&ui[ti + 1][k];
        float4 b0 = *(const float4*)&uj[tj][k];
        float4 b1 = *(const float4*)&uj[tj + 1][k];
        dot[0][0] += a0.x*b0.x + a0.y*b0.y + a0.z*b0.z + a0.w*b0.w;
        dot[0][1] += a0.x*b1.x + a0.y*b1.y + a0.z*b1.z + a0.w*b1.w;
        dot[1][0] += a1.x*b0.x + a1.y*b0.y + a1.z*b0.z + a1.w*b0.w;
        dot[1][1] += a1.x*b1.x + a1.y*b1.y + a1.z*b1.z + a1.w*b1.w;
    }

    float ps = 0.f, pc = 0.f, ns = 0.f, nc = 0.f;
#pragma unroll
    for (int ii = 0; ii < 2; ++ii)
#pragma unroll
        for (int jj = 0; jj < 2; ++jj) {
            int gi = i0 + ti + ii, gj = j0 + tj + jj;
            float sq = sni[ti + ii] + snj[tj + jj] - 2.f * dot[ii][jj];
            float dist = sq > 0.f ? sqrtf(fmaxf(sq, 1e-16f)) : 0.f;
            bool same = (li[ti + ii] == lj[tj + jj]);
            if (same) {
                if (gi != gj) { ps += fmaxf(dist - 0.7f, 0.f); pc += 1.f; }
            } else {
                ns += fmaxf(1.4f - dist, 0.f); nc += 1.f;
            }
        }

#pragma unroll
    for (int off = 32; off; off >>= 1) {
        ps += __shfl_xor(ps, off); pc += __shfl_xor(pc, off);
        ns += __shfl_xor(ns, off); nc += __shfl_xor(nc, off);
    }
    const int wv = t >> 6, ln = t & 63;
    if (ln == 0) { red[0][wv] = ps; red[1][wv] = pc; red[2][wv] = ns; red[3][wv] = nc; }
    __syncthreads();
    if (t == 0) {
        float a = red[0][0] + red[0][1] + red[0][2] + red[0][3];
        float b = red[1][0] + red[1][1] + red[1][2] + red[1][3];
        float c = red[2][0] + red[2][1] + red[2][2] + red[2][3];
        float d = red[3][0] + red[3][1] + red[3][2] + red[3][3];
        atomicAdd(part + 1, a); atomicAdd(part + 2, b);
        atomicAdd(part + 3, c); atomicAdd(part + 4, d);
    }
}

// ---------------------------------------------------------------------------
// K7: finalize scalar loss.
// ---------------------------------------------------------------------------
__global__ void finalize(const float* __restrict__ part, float* __restrict__ out)
{
    if (threadIdx.x == 0 && blockIdx.x == 0) {
        float cls = part[0] / (float)B_;
        float pos = part[1] / fmaxf(part[2], 1.f);
        float neg = part[3] / fmaxf(part[4], 1.f);
        out[0] = cls + pos + neg;
    }
}

extern "C" void kernel_launch(void* const* d_in, const int* in_sizes, int n_in,
                              void* d_out, int out_size, void* d_ws, size_t ws_size,
                              hipStream_t stream)
{
    const float* x    = (const float*)d_in[0];
    const int*   lb   = (const int*)d_in[1];
    const float* mem  = (const float*)d_in[2];
    const float* fc_w = (const float*)d_in[3];
    const float* fc_b = (const float*)d_in[4];
    const float* p1w  = (const float*)d_in[5];
    const float* p1b  = (const float*)d_in[6];
    const float* p2w  = (const float*)d_in[7];
    const float* p2b  = (const float*)d_in[8];

    float* ws     = (float*)d_ws;
    float* mh     = ws + OFF_MH;
    float* xh     = ws + OFF_XH;
    float* logits = ws + OFF_LOGITS;
    float* u      = ws + OFF_U;
    float* sqn    = ws + OFF_SQN;
    float* part   = ws + OFF_PART;

    hipMemsetAsync(part, 0, 8 * sizeof(float), stream);

    // K1: mh = mem @ Wm^T   (Wm = fc_w[:, 768:])
    gemm_nt<<<dim3(3, 24), 256, 0, stream>>>(mem, D_, C_, fc_w, TWOD, D_,
                                             nullptr, mh, TWOD, TWOD, D_);
    // K2: xh = x @ Wx^T + fc_b  (Wx = fc_w[:, :768])
    gemm_nt<<<dim3(16, 24), 256, 0, stream>>>(x, D_, B_, fc_w, TWOD, 0,
                                              fc_b, xh, TWOD, TWOD, D_);
    // K3: logits (seen + unseen) and raw u projection
    fused_cols<<<dim3(256, 4), 256, 0, stream>>>(xh, mh, p1w, p1b, p2w, p2b,
                                                 logits, u);
    // K4: normalize u rows
    norm_rows<<<256, 256, 0, stream>>>(u, sqn);
    // K5: classification loss partial sum
    cls_loss<<<256, 256, 0, stream>>>(logits, lb, part);
    // K6: pairwise margin losses
    pair_loss<<<dim3(32, 32), 256, 0, stream>>>(u, sqn, lb, part);
    // K7: write scalar output
    finalize<<<1, 64, 0, stream>>>(part, (float*)d_out);
}

// Round 2
// 313.271 us; speedup vs baseline: 1.0834x; 1.0834x over previous
//
#include <hip/hip_runtime.h>
#include <math.h>

// Problem constants
#define B_    1024
#define D_    768
#define C_    150
#define P_    64
#define TWOD  1536
#define NCLS  151   // C+1
#define NCOL  215   // 151 seen/unseen + 64 u-projection cols

#define ECHUNKS 8
#define ECHUNK  192   // TWOD / ECHUNKS
#define ESTEP   16

// Workspace layout (float offsets)
#define OFF_MH     0
#define OFF_XH     (C_ * TWOD)                      // 230400
#define OFF_LOGITS (OFF_XH + B_ * TWOD)             // 1803264
#define OFF_U      (OFF_LOGITS + B_ * NCLS)
#define OFF_SQN    (OFF_U + B_ * P_)
#define OFF_PART   (OFF_SQN + B_)
// partials: [0]=cls_sum [1]=pos_sum [2]=pos_cnt [3]=neg_sum [4]=neg_cnt

// ---------------------------------------------------------------------------
// K1/K2: Out[m,n] = sum_k A[m,k] * Bw[n, boff+k]  (+ bias[n])
// ---------------------------------------------------------------------------
__global__ __launch_bounds__(256) void gemm_nt(
    const float* __restrict__ A, int lda, int M,
    const float* __restrict__ Bw, int ldb, int boff,
    const float* __restrict__ bias,
    float* __restrict__ Out, int ldo, int N, int K)
{
    __shared__ float As[16][68];   // [k][m], +4 pad
    __shared__ float Bs[16][68];   // [k][n]
    const int t  = threadIdx.x;
    const int bm = blockIdx.x * 64;
    const int bn = blockIdx.y * 64;
    const int tm = t & 15, tn = t >> 4;
    const int lrow = t >> 2;         // 0..63
    const int lk   = (t & 3) * 4;    // 0,4,8,12

    float acc[4][4] = {};

    for (int k0 = 0; k0 < K; k0 += 16) {
        int gr  = bm + lrow;
        int grc = gr < M ? gr : (M - 1);
        const float4 av = *(const float4*)&A[(size_t)grc * lda + k0 + lk];
        As[lk + 0][lrow] = av.x; As[lk + 1][lrow] = av.y;
        As[lk + 2][lrow] = av.z; As[lk + 3][lrow] = av.w;
        const float4 bv = *(const float4*)&Bw[(size_t)(bn + lrow) * ldb + boff + k0 + lk];
        Bs[lk + 0][lrow] = bv.x; Bs[lk + 1][lrow] = bv.y;
        Bs[lk + 2][lrow] = bv.z; Bs[lk + 3][lrow] = bv.w;
        __syncthreads();
#pragma unroll
        for (int kk = 0; kk < 16; ++kk) {
            const float4 a4 = *(const float4*)&As[kk][tm * 4];
            const float4 b4 = *(const float4*)&Bs[kk][tn * 4];
            const float a[4]  = {a4.x, a4.y, a4.z, a4.w};
            const float bb[4] = {b4.x, b4.y, b4.z, b4.w};
#pragma unroll
            for (int i = 0; i < 4; ++i)
#pragma unroll
                for (int j = 0; j < 4; ++j)
                    acc[i][j] = fmaf(a[i], bb[j], acc[i][j]);
        }
        __syncthreads();
    }

#pragma unroll
    for (int i = 0; i < 4; ++i) {
        int gm = bm + tm * 4 + i;
        if (gm >= M) continue;
#pragma unroll
        for (int j = 0; j < 4; ++j) {
            int gn = bn + tn * 4 + j;
            float bv = bias ? bias[gn] : 0.f;
            Out[(size_t)gm * ldo + gn] = acc[i][j] + bv;
        }
    }
}

// ---------------------------------------------------------------------------
// K3: fused tile kernel: out[b,c] = sum_e relu(xh[b,e] + m[c,e]) * w[c,e]
//   c <150: m = mh[c],  w = p1      (seen logits)
//   c==150: m = 0,      w = p1      (unseen logit)
//   c in [151,215): m = 0, w = p2w[c-151]   (u projection)
// 64 b x 64 c tile per block, 4x4 per thread, e split 8 ways (atomicAdd).
// ---------------------------------------------------------------------------
__global__ __launch_bounds__(256) void fused_tile(
    const float* __restrict__ xh,   // [B][1536]
    const float* __restrict__ mh,   // [150][1536]
    const float* __restrict__ p1w, const float* __restrict__ p1b,
    const float* __restrict__ p2w, const float* __restrict__ p2b,
    float* __restrict__ logits,     // [B][151] (pre-zeroed)
    float* __restrict__ u)          // [B][64]  (pre-zeroed)
{
    __shared__ float xT[ESTEP][64];
    __shared__ float mT[ESTEP][64];
    __shared__ float wT[ESTEP][64];

    const int t  = threadIdx.x;
    const int b0 = blockIdx.x * 64;
    const int c0 = blockIdx.y * 64;
    const int e0 = blockIdx.z * ECHUNK;
    const int tm = t & 15, tn = t >> 4;

    // staging: thread stages 4 consecutive e's for one b-row and one c-col
    const int sb = t >> 2;        // 0..63
    const int se = (t & 3) * 4;   // 0,4,8,12

    const int   gc    = c0 + sb;
    const bool  cseen = gc < C_;
    const bool  cp1   = gc < NCLS;
    const bool  cu    = (gc >= NCLS) && (gc < NCOL);
    const float* mrow = mh + (size_t)(cseen ? gc : 0) * TWOD;
    const float* wrow = cu ? (p2w + (size_t)(gc - NCLS) * TWOD) : p1w;
    const float* xrow = xh + (size_t)(b0 + sb) * TWOD;

    float acc[4][4] = {};

    for (int es = 0; es < ECHUNK; es += ESTEP) {
        const int eb = e0 + es + se;
        float4 xv = *(const float4*)&xrow[eb];
        float4 mv = cseen ? *(const float4*)&mrow[eb] : make_float4(0.f, 0.f, 0.f, 0.f);
        float4 wv = (cp1 || cu) ? *(const float4*)&wrow[eb] : make_float4(0.f, 0.f, 0.f, 0.f);
        __syncthreads();   // previous step's reads done
        xT[se + 0][sb] = xv.x; xT[se + 1][sb] = xv.y;
        xT[se + 2][sb] = xv.z; xT[se + 3][sb] = xv.w;
        mT[se + 0][sb] = mv.x; mT[se + 1][sb] = mv.y;
        mT[se + 2][sb] = mv.z; mT[se + 3][sb] = mv.w;
        wT[se + 0][sb] = wv.x; wT[se + 1][sb] = wv.y;
        wT[se + 2][sb] = wv.z; wT[se + 3][sb] = wv.w;
        __syncthreads();
#pragma unroll
        for (int e = 0; e < ESTEP; ++e) {
            const float4 a4 = *(const float4*)&xT[e][tm * 4];
            const float4 m4 = *(const float4*)&mT[e][tn * 4];
            const float4 w4 = *(const float4*)&wT[e][tn * 4];
            const float a[4] = {a4.x, a4.y, a4.z, a4.w};
            const float m[4] = {m4.x, m4.y, m4.z, m4.w};
            const float w[4] = {w4.x, w4.y, w4.z, w4.w};
#pragma unroll
            for (int i = 0; i < 4; ++i)
#pragma unroll
                for (int j = 0; j < 4; ++j)
                    acc[i][j] = fmaf(fmaxf(a[i] + m[j], 0.f), w[j], acc[i][j]);
        }
    }

    const bool addb = (blockIdx.z == 0);
#pragma unroll
    for (int j = 0; j < 4; ++j) {
        const int c = c0 + tn * 4 + j;
        if (c >= NCOL) continue;
        const float bv = addb ? (c < NCLS ? p1b[0] : p2b[c - NCLS]) : 0.f;
#pragma unroll
        for (int i = 0; i < 4; ++i) {
            const int gb = b0 + tm * 4 + i;
            if (c < NCLS) atomicAdd(&logits[(size_t)gb * NCLS + c], acc[i][j] + bv);
            else          atomicAdd(&u[(size_t)gb * P_ + (c - NCLS)], acc[i][j] + bv);
        }
    }
}

// ---------------------------------------------------------------------------
// K4: row-normalize u, store sq_n. One wave per row.
// ---------------------------------------------------------------------------
__global__ __launch_bounds__(256) void norm_rows(float* __restrict__ u,
                                                 float* __restrict__ sqn)
{
    const int wave = threadIdx.x >> 6;
    const int lane = threadIdx.x & 63;
    const int row  = blockIdx.x * 4 + wave;
    float v = u[(size_t)row * P_ + lane];
    float s = v * v;
#pragma unroll
    for (int off = 32; off; off >>= 1) s += __shfl_xor(s, off);
    float inv = 1.f / fmaxf(sqrtf(s), 1e-12f);
    u[(size_t)row * P_ + lane] = v * inv;
    if (lane == 0) sqn[row] = s * inv * inv;
}

// ---------------------------------------------------------------------------
// K5: classification loss. One wave per row b.
// ---------------------------------------------------------------------------
__global__ __launch_bounds__(256) void cls_loss(const float* __restrict__ logits,
                                                const int* __restrict__ lb,
                                                float* __restrict__ part)
{
    const int wave = threadIdx.x >> 6;
    const int lane = threadIdx.x & 63;
    const int b    = blockIdx.x * 4 + wave;
    const float* row = logits + (size_t)b * NCLS;
    const int l = lb[b];

    float mx = -1e30f;
    for (int j = lane; j < NCLS; j += 64) {
        bool excl = (j == l) && (l < C_);
        float v = row[j];
        if (!excl) mx = fmaxf(mx, v);
    }
#pragma unroll
    for (int off = 32; off; off >>= 1) mx = fmaxf(mx, __shfl_xor(mx, off));
    float se = 0.f;
    for (int j = lane; j < NCLS; j += 64) {
        bool excl = (j == l) && (l < C_);
        if (!excl) se += expf(row[j] - mx);
    }
#pragma unroll
    for (int off = 32; off; off >>= 1) se += __shfl_xor(se, off);

    if (lane == 0) {
        float l150 = row[C_];
        float loss2 = mx + logf(se) - l150;
        float loss1 = 0.f;
        if (l < C_) {
            float a  = row[l];
            float m2 = fmaxf(a, l150);
            loss1 = m2 - a + logf(expf(a - m2) + expf(l150 - m2));
        }
        atomicAdd(part + 0, loss1 + loss2);
    }
}

// ---------------------------------------------------------------------------
// K6: pairwise margin losses. 32x32 pair tile per block, 2x2 per thread.
// ---------------------------------------------------------------------------
__global__ __launch_bounds__(256) void pair_loss(
    const float* __restrict__ u, const float* __restrict__ sqn,
    const int* __restrict__ lb, float* __restrict__ part)
{
    __shared__ float ui[32][68];
    __shared__ float uj[32][68];
    __shared__ float sni[32], snj[32];
    __shared__ int   li[32],  lj[32];
    __shared__ float red[4][4];

    const int t  = threadIdx.x;
    const int i0 = blockIdx.x * 32, j0 = blockIdx.y * 32;

    for (int idx = t; idx < 512; idx += 256) {
        int r = idx >> 4, e4 = idx & 15;
        ((float4*)&ui[r][0])[e4] = ((const float4*)(u + (size_t)(i0 + r) * P_))[e4];
        ((float4*)&uj[r][0])[e4] = ((const float4*)(u + (size_t)(j0 + r) * P_))[e4];
    }
    if (t < 32) {
        sni[t] = sqn[i0 + t]; li[t] = lb[i0 + t];
        snj[t] = sqn[j0 + t]; lj[t] = lb[j0 + t];
    }
    __syncthreads();

    const int ti = (t & 15) * 2, tj = (t >> 4) * 2;
    float dot[2][2] = {};
#pragma unroll
    for (int k = 0; k < 64; k += 4) {
        float4 a0 = *(const float4*)&ui[ti][k];
        float4 a1 = *(const float4*)&ui[ti + 1][k];
        float4 b0 = *(const float4*)&uj[tj][k];
        float4 b1 = *(const float4*)&uj[tj + 1][k];
        dot[0][0] += a0.x*b0.x + a0.y*b0.y + a0.z*b0.z + a0.w*b0.w;
        dot[0][1] += a0.x*b1.x + a0.y*b1.y + a0.z*b1.z + a0.w*b1.w;
        dot[1][0] += a1.x*b0.x + a1.y*b0.y + a1.z*b0.z + a1.w*b0.w;
        dot[1][1] += a1.x*b1.x + a1.y*b1.y + a1.z*b1.z + a1.w*b1.w;
    }

    float ps = 0.f, pc = 0.f, ns = 0.f, nc = 0.f;
#pragma unroll
    for (int ii = 0; ii < 2; ++ii)
#pragma unroll
        for (int jj = 0; jj < 2; ++jj) {
            int gi = i0 + ti + ii, gj = j0 + tj + jj;
            float sq = sni[ti + ii] + snj[tj + jj] - 2.f * dot[ii][jj];
            float dist = sq > 0.f ? sqrtf(fmaxf(sq, 1e-16f)) : 0.f;
            bool same = (li[ti + ii] == lj[tj + jj]);
            if (same) {
                if (gi != gj) { ps += fmaxf(dist - 0.7f, 0.f); pc += 1.f; }
            } else {
                ns += fmaxf(1.4f - dist, 0.f); nc += 1.f;
            }
        }

#pragma unroll
    for (int off = 32; off; off >>= 1) {
        ps += __shfl_xor(ps, off); pc += __shfl_xor(pc, off);
        ns += __shfl_xor(ns, off); nc += __shfl_xor(nc, off);
    }
    const int wv = t >> 6, ln = t & 63;
    if (ln == 0) { red[0][wv] = ps; red[1][wv] = pc; red[2][wv] = ns; red[3][wv] = nc; }
    __syncthreads();
    if (t == 0) {
        float a = red[0][0] + red[0][1] + red[0][2] + red[0][3];
        float b = red[1][0] + red[1][1] + red[1][2] + red[1][3];
        float c = red[2][0] + red[2][1] + red[2][2] + red[2][3];
        float d = red[3][0] + red[3][1] + red[3][2] + red[3][3];
        atomicAdd(part + 1, a); atomicAdd(part + 2, b);
        atomicAdd(part + 3, c); atomicAdd(part + 4, d);
    }
}

// ---------------------------------------------------------------------------
// K7: finalize scalar loss.
// ---------------------------------------------------------------------------
__global__ void finalize(const float* __restrict__ part, float* __restrict__ out)
{
    if (threadIdx.x == 0 && blockIdx.x == 0) {
        float cls = part[0] / (float)B_;
        float pos = part[1] / fmaxf(part[2], 1.f);
        float neg = part[3] / fmaxf(part[4], 1.f);
        out[0] = cls + pos + neg;
    }
}

extern "C" void kernel_launch(void* const* d_in, const int* in_sizes, int n_in,
                              void* d_out, int out_size, void* d_ws, size_t ws_size,
                              hipStream_t stream)
{
    const float* x    = (const float*)d_in[0];
    const int*   lb   = (const int*)d_in[1];
    const float* mem  = (const float*)d_in[2];
    const float* fc_w = (const float*)d_in[3];
    const float* fc_b = (const float*)d_in[4];
    const float* p1w  = (const float*)d_in[5];
    const float* p1b  = (const float*)d_in[6];
    const float* p2w  = (const float*)d_in[7];
    const float* p2b  = (const float*)d_in[8];

    float* ws     = (float*)d_ws;
    float* mh     = ws + OFF_MH;
    float* xh     = ws + OFF_XH;
    float* logits = ws + OFF_LOGITS;
    float* u      = ws + OFF_U;
    float* sqn    = ws + OFF_SQN;
    float* part   = ws + OFF_PART;

    // zero the atomic accumulation targets (logits, u, sqn, part)
    hipMemsetAsync(logits, 0,
                   (size_t)(B_ * NCLS + B_ * P_ + B_ + 8) * sizeof(float), stream);

    // K1: mh = mem @ Wm^T   (Wm = fc_w[:, 768:])
    gemm_nt<<<dim3(3, 24), 256, 0, stream>>>(mem, D_, C_, fc_w, TWOD, D_,
                                             nullptr, mh, TWOD, TWOD, D_);
    // K2: xh = x @ Wx^T + fc_b  (Wx = fc_w[:, :768])
    gemm_nt<<<dim3(16, 24), 256, 0, stream>>>(x, D_, B_, fc_w, TWOD, 0,
                                              fc_b, xh, TWOD, TWOD, D_);
    // K3: logits (seen + unseen) and raw u projection, e-split with atomics
    fused_tile<<<dim3(16, 4, ECHUNKS), 256, 0, stream>>>(xh, mh, p1w, p1b,
                                                         p2w, p2b, logits, u);
    // K4: normalize u rows
    norm_rows<<<256, 256, 0, stream>>>(u, sqn);
    // K5: classification loss partial sum
    cls_loss<<<256, 256, 0, stream>>>(logits, lb, part);
    // K6: pairwise margin losses
    pair_loss<<<dim3(32, 32), 256, 0, stream>>>(u, sqn, lb, part);
    // K7: write scalar output
    finalize<<<1, 64, 0, stream>>>(part, (float*)d_out);
}